// Round 4
// baseline (421.565 us; speedup 1.0000x reference)
//
#include <hip/hip_runtime.h>

// GTEAST layer, round 4: 32x32x16 MFMA (2 dsts per wave-tile), prep fused into K1.
// N_SRC=100000, N_DST=50000, DEG=16, NODE_IN=128, EDGE_IN=64, HID=64, E=800000
// Fold: a = leaky_relu(ef @ (Wa@wa) + ba.wa) (fp32, exact; computed per-block in K1)
// MFMA 32x32x16 bf16 layouts (m74/m101-verified):
//   A-frag: lane l holds A[m=l&31][k=8*(l>>5)+j], j=0..7
//   B-frag: lane l holds B^T[n=l&31][k=8*(l>>5)+j]
//   C/D:    lane l holds C[row=(reg&3)+8*(reg>>2)+4*(l>>5)][col=l&31], reg=0..15
// K1: per wave-iter: 2 dsts (32 edges). e-GEMM -> E-transpose in LDS -> m-GEMM
// (K=192, kc-outer streaming A) -> sparsemax (16-lane bitonic) -> h_neigh.
// h_neigh staged fp32 in d_out; K2 rewrites in place.

#define ND 50000

typedef __bf16 bf16x8 __attribute__((ext_vector_type(8)));
typedef float f32x16 __attribute__((ext_vector_type(16)));

__device__ __forceinline__ void sync_wave() {
  asm volatile("s_waitcnt lgkmcnt(0)" ::: "memory");
}

__device__ __forceinline__ unsigned short f2bf(float x) {
  unsigned u = __float_as_uint(x);
  u += 0x7fffu + ((u >> 16) & 1u);
  return (unsigned short)(u >> 16);
}

union Frag8 { bf16x8 v; unsigned u32[4]; };

// two float4 -> bf16x8 (round-half-up + v_perm pack)
__device__ __forceinline__ bf16x8 pack44(float4 a, float4 b) {
  Frag8 f;
  f.u32[0] = __builtin_amdgcn_perm(__float_as_uint(a.y) + 0x8000u,
                                   __float_as_uint(a.x) + 0x8000u, 0x07060302);
  f.u32[1] = __builtin_amdgcn_perm(__float_as_uint(a.w) + 0x8000u,
                                   __float_as_uint(a.z) + 0x8000u, 0x07060302);
  f.u32[2] = __builtin_amdgcn_perm(__float_as_uint(b.y) + 0x8000u,
                                   __float_as_uint(b.x) + 0x8000u, 0x07060302);
  f.u32[3] = __builtin_amdgcn_perm(__float_as_uint(b.w) + 0x8000u,
                                   __float_as_uint(b.z) + 0x8000u, 0x07060302);
  return f.v;
}

#define MFMA32(a, b, c) __builtin_amdgcn_mfma_f32_32x32x16_bf16((a), (b), (c), 0, 0, 0)

__device__ __forceinline__ f32x16 fzero16() {
  f32x16 c;
  #pragma unroll
  for (int r = 0; r < 16; ++r) c[r] = 0.f;
  return c;
}

// ---------- K1: fused prep + e_out + attention + m + sparsemax + h_neigh ----------
extern "C" __global__ void __launch_bounds__(256, 2)
gteast_edge(const float* __restrict__ nf, const float* __restrict__ ef,
            const int* __restrict__ src,
            const float* __restrict__ Wa, const float* __restrict__ ba,
            const float* __restrict__ wa,
            const float* __restrict__ We, const float* __restrict__ be,
            const float* __restrict__ Wo, const float* __restrict__ bo,
            float* __restrict__ hn_out) {
  __shared__ unsigned short WoT[64 * 200];     // W^T[n][k] 25.6 KB
  __shared__ unsigned short WeT[64 * 72];      // 9.2 KB
  __shared__ unsigned short Et[4][32 * 72];    // per-wave e_out tile [m][h], 18.4 KB
  __shared__ float vls[65];                    // v[64], c
  __shared__ float pr[260];

  const int tid = threadIdx.x;
  for (int i = tid; i < 64 * 64; i += 256) WeT[(i & 63) * 72 + (i >> 6)] = f2bf(We[i]);
  for (int i = tid; i < 192 * 64; i += 256) WoT[(i & 63) * 200 + (i >> 6)] = f2bf(Wo[i]);
  {  // prep: v = Wa@wa, c = ba.wa (redundant per block, cheap)
    const int k = tid >> 2, p = tid & 3;
    float s = 0.f;
    for (int h = 16 * p; h < 16 * p + 16; ++h) s += Wa[k * 64 + h] * wa[h];
    pr[tid] = s;
    if (tid < 4) {
      float sc = 0.f;
      for (int h = 16 * tid; h < 16 * tid + 16; ++h) sc += ba[h] * wa[h];
      pr[256 + tid] = sc;
    }
  }
  __syncthreads();
  if (tid < 64) vls[tid] = pr[4 * tid] + pr[4 * tid + 1] + pr[4 * tid + 2] + pr[4 * tid + 3];
  if (tid == 64) vls[64] = pr[256] + pr[257] + pr[258] + pr[259];
  __syncthreads();

  const int lane = tid & 63, w = tid >> 6;
  const int m = lane & 31, h8 = lane >> 5, t16 = lane & 15;
  const int wid = blockIdx.x * 4 + w;  // 0..3127; 3125 active
  if (wid >= 3125) return;

  unsigned short* E = Et[w];
  const float cval = vls[64];
  float beL[2], boL[2];
  beL[0] = be[m]; beL[1] = be[32 + m];
  boL[0] = bo[m]; boL[1] = bo[32 + m];

  int s_cur = src[wid * 256 + m];  // src for it=0, edge m

  #pragma unroll 2
  for (int it = 0; it < 8; ++it) {
    const int n0 = wid * 16 + it * 2;
    const long e0 = (long)wid * 256 + it * 32;

    // prefetch next iteration's src (covered by whole body)
    const int s_nxt = (it < 7) ? src[e0 + 32 + m] : 0;

    // --- issue ef loads (8 f4) + nf batch1 (8 f4) ---
    const float* ep = ef + (e0 + m) * 64 + h8 * 8;
    float4 er[8];
    #pragma unroll
    for (int kc = 0; kc < 4; ++kc) {
      er[2 * kc] = *reinterpret_cast<const float4*>(ep + kc * 16);
      er[2 * kc + 1] = *reinterpret_cast<const float4*>(ep + kc * 16 + 4);
    }
    const float* hp = nf + (long)s_cur * 128 + h8 * 8;
    float4 nr[8];
    #pragma unroll
    for (int kc = 0; kc < 4; ++kc) {
      nr[2 * kc] = *reinterpret_cast<const float4*>(hp + kc * 16);
      nr[2 * kc + 1] = *reinterpret_cast<const float4*>(hp + kc * 16 + 4);
    }

    // --- fp32 logit partial + pack ef frags ---
    bf16x8 efF[4];
    float ap = 0.f;
    #pragma unroll
    for (int kc = 0; kc < 4; ++kc) {
      float4 a0 = er[2 * kc], a1 = er[2 * kc + 1];
      float4 v0 = *reinterpret_cast<const float4*>(&vls[kc * 16 + h8 * 8]);
      float4 v1 = *reinterpret_cast<const float4*>(&vls[kc * 16 + h8 * 8 + 4]);
      ap += a0.x * v0.x + a0.y * v0.y + a0.z * v0.z + a0.w * v0.w;
      ap += a1.x * v1.x + a1.y * v1.y + a1.z * v1.z + a1.w * v1.w;
      efF[kc] = pack44(a0, a1);
    }
    ap += __shfl_xor(ap, 32);  // k-halves
    float a = ap + cval;
    a = a > 0.f ? a : 0.01f * a;  // leaky_relu; lane holds edge m's logit

    // --- e-GEMM: e_out = relu(ef @ We + be), write transposed tile to LDS ---
    #pragma unroll
    for (int nt = 0; nt < 2; ++nt) {
      f32x16 c = fzero16();
      #pragma unroll
      for (int kc = 0; kc < 4; ++kc)
        c = MFMA32(efF[kc],
                   *reinterpret_cast<const bf16x8*>(&WeT[(nt * 32 + m) * 72 + kc * 16 + h8 * 8]), c);
      #pragma unroll
      for (int r = 0; r < 16; ++r) {
        const int row = (r & 3) + 8 * (r >> 2) + 4 * h8;
        E[row * 72 + nt * 32 + m] = f2bf(fmaxf(c[r] + beL[nt], 0.f));
      }
    }
    sync_wave();

    // --- issue nf batch2 (kc 4..7) ---
    float4 nr2[8];
    #pragma unroll
    for (int kc = 0; kc < 4; ++kc) {
      nr2[2 * kc] = *reinterpret_cast<const float4*>(hp + 64 + kc * 16);
      nr2[2 * kc + 1] = *reinterpret_cast<const float4*>(hp + 64 + kc * 16 + 4);
    }

    // --- m-GEMM: K=192 kc-outer, A-frags streamed ---
    f32x16 cM0 = fzero16(), cM1 = fzero16();
    #pragma unroll
    for (int kc = 0; kc < 12; ++kc) {
      bf16x8 af;
      if (kc < 4) af = pack44(nr[2 * kc], nr[2 * kc + 1]);
      else if (kc < 8) af = pack44(nr2[2 * (kc - 4)], nr2[2 * (kc - 4) + 1]);
      else af = *reinterpret_cast<const bf16x8*>(&E[m * 72 + (kc - 8) * 16 + h8 * 8]);
      cM0 = MFMA32(af, *reinterpret_cast<const bf16x8*>(&WoT[m * 200 + kc * 16 + h8 * 8]), cM0);
      cM1 = MFMA32(af, *reinterpret_cast<const bf16x8*>(&WoT[(32 + m) * 200 + kc * 16 + h8 * 8]), cM1);
    }
    sync_wave();  // E reads drained before next iteration's writes
    #pragma unroll
    for (int r = 0; r < 16; ++r) {
      cM0[r] = fmaxf(cM0[r] + boL[0], 0.f);
      cM1[r] = fmaxf(cM1[r] + boL[1], 0.f);
    }

    // --- sparsemax per 16-lane group (lanes 0-15: dst0, 16-31: dst1, dup in h8=1) ---
    float z = a;
    #pragma unroll
    for (int k = 2; k <= 16; k <<= 1) {
      #pragma unroll
      for (int j = k >> 1; j > 0; j >>= 1) {
        float o = __shfl_xor(z, j);
        const bool upper = (t16 & j) != 0;
        const bool desc = (t16 & k) == 0;
        z = (upper != desc) ? fmaxf(z, o) : fminf(z, o);
      }
    }
    float cs = z;
    #pragma unroll
    for (int off = 1; off < 16; off <<= 1) {
      float o = __shfl_up(cs, off, 16);
      cs += (t16 >= off) ? o : 0.f;
    }
    const bool gt = 1.f + (float)(t16 + 1) * z > cs;
    float kf = gt ? (float)(t16 + 1) : 0.f;
    float sv = gt ? z : 0.f;
    #pragma unroll
    for (int mm = 1; mm < 16; mm <<= 1) {
      kf = fmaxf(kf, __shfl_xor(kf, mm));
      sv += __shfl_xor(sv, mm);
    }
    const float tau = (sv - 1.f) / kf;
    const float alpha = fmaxf(a - tau, 0.f);  // own edge m's weight

    // --- h_neigh: alpha-weighted row-sum of C tiles ---
    float al[16];
    #pragma unroll
    for (int r = 0; r < 16; ++r)
      al[r] = __shfl(alpha, (r & 3) + 8 * (r >> 2) + 4 * h8);
    float p00 = 0.f, p01 = 0.f, p10 = 0.f, p11 = 0.f;
    #pragma unroll
    for (int r = 0; r < 8; ++r) {
      p00 += al[r] * cM0[r];      p01 += al[r] * cM1[r];        // dst0 (rows<16)
      p10 += al[8 + r] * cM0[8 + r]; p11 += al[8 + r] * cM1[8 + r];  // dst1
    }
    p00 += __shfl_xor(p00, 32); p01 += __shfl_xor(p01, 32);
    p10 += __shfl_xor(p10, 32); p11 += __shfl_xor(p11, 32);
    const float v0 = h8 ? p10 : p00;
    const float v1 = h8 ? p11 : p01;
    hn_out[(long)(n0 + h8) * 64 + m] = v0;
    hn_out[(long)(n0 + h8) * 64 + 32 + m] = v1;

    s_cur = s_nxt;
  }
}

// ---------- K2: out = relu([h_dst | h_neigh] @ Wn + bn), in place ----------
extern "C" __global__ void __launch_bounds__(256, 2)
gteast_out(const float* __restrict__ nf, const float* __restrict__ Wn,
           const float* __restrict__ bn, float* __restrict__ out) {
  __shared__ unsigned short WnT[64 * 200];
  const int tid = threadIdx.x;
  for (int i = tid; i < 192 * 64; i += 256) WnT[(i & 63) * 200 + (i >> 6)] = f2bf(Wn[i]);
  __syncthreads();

  const int lane = tid & 63, w = tid >> 6;
  const int m = lane & 31, h8 = lane >> 5;
  const int tile = blockIdx.x * 4 + w;  // 0..1563; 1563 active (ceil(50000/32))
  if (tile >= 1563) return;
  const int r0 = tile * 32;

  float bnL[2];
  bnL[0] = bn[m]; bnL[1] = bn[32 + m];

  const float* hp = nf + (long)(r0 + m) * 128 + h8 * 8;        // rows < 100000, safe
  const int hr = min(r0 + m, ND - 1);                          // clamp tail for hn reads
  const float* gp = out + (long)hr * 64 + h8 * 8;

  float4 nr[8], nr2[8], gr[8];
  #pragma unroll
  for (int kc = 0; kc < 4; ++kc) {
    nr[2 * kc] = *reinterpret_cast<const float4*>(hp + kc * 16);
    nr[2 * kc + 1] = *reinterpret_cast<const float4*>(hp + kc * 16 + 4);
  }
  #pragma unroll
  for (int kc = 0; kc < 4; ++kc) {
    nr2[2 * kc] = *reinterpret_cast<const float4*>(hp + 64 + kc * 16);
    nr2[2 * kc + 1] = *reinterpret_cast<const float4*>(hp + 64 + kc * 16 + 4);
  }
  #pragma unroll
  for (int kc = 0; kc < 4; ++kc) {
    gr[2 * kc] = *reinterpret_cast<const float4*>(gp + kc * 16);
    gr[2 * kc + 1] = *reinterpret_cast<const float4*>(gp + kc * 16 + 4);
  }

  f32x16 c0 = fzero16(), c1 = fzero16();
  #pragma unroll
  for (int kc = 0; kc < 12; ++kc) {
    bf16x8 af;
    if (kc < 4) af = pack44(nr[2 * kc], nr[2 * kc + 1]);
    else if (kc < 8) af = pack44(nr2[2 * (kc - 4)], nr2[2 * (kc - 4) + 1]);
    else af = pack44(gr[2 * (kc - 8)], gr[2 * (kc - 8) + 1]);
    c0 = MFMA32(af, *reinterpret_cast<const bf16x8*>(&WnT[m * 200 + kc * 16 + h8 * 8]), c0);
    c1 = MFMA32(af, *reinterpret_cast<const bf16x8*>(&WnT[(32 + m) * 200 + kc * 16 + h8 * 8]), c1);
  }

  #pragma unroll
  for (int r = 0; r < 16; ++r) {
    const int row = (r & 3) + 8 * (r >> 2) + 4 * h8;
    const int grow = r0 + row;
    if (grow < ND) {
      out[(long)grow * 64 + m] = fmaxf(c0[r] + bnL[0], 0.f);
      out[(long)grow * 64 + 32 + m] = fmaxf(c1[r] + bnL[1], 0.f);
    }
  }
}

extern "C" void kernel_launch(void* const* d_in, const int* in_sizes, int n_in,
                              void* d_out, int out_size, void* d_ws, size_t ws_size,
                              hipStream_t stream) {
  const float* nf = (const float*)d_in[0];
  const float* ef = (const float*)d_in[1];
  const int* si   = (const int*)d_in[2];
  const float* We = (const float*)d_in[3];
  const float* be = (const float*)d_in[4];
  const float* Wa = (const float*)d_in[5];
  const float* ba = (const float*)d_in[6];
  const float* wa = (const float*)d_in[7];
  const float* Wo = (const float*)d_in[8];
  const float* bo = (const float*)d_in[9];
  const float* Wn = (const float*)d_in[10];
  const float* bn = (const float*)d_in[11];
  float* out = (float*)d_out;

  gteast_edge<<<782, 256, 0, stream>>>(nf, ef, si, Wa, ba, wa, We, be, Wo, bo, out);
  gteast_out<<<391, 256, 0, stream>>>(nf, Wn, bn, out);
}